// Round 11
// baseline (612.932 us; speedup 1.0000x reference)
//
#include <hip/hip_runtime.h>

// ---- problem constants (R2-exact math) ----
// S = 2.45229158;  D = delta*S = sqrt(log2 e)/2;  4*D^2 = log2(e)
// g_k (k = 10c + r): u = dS - 10c*D;  g = 2^{-u^2} * Ac^r * e^{-r^2/4}
// Ac = Ap * e^{-5c}, Ap = 2^{2D*dS}
#define S_C     2.45229158f
#define TWO_DS  1.20112241f
#define TEN_D   6.00560980f
#define E5_1 6.73794700e-3f
#define E5_2 4.53999298e-5f
#define E5_3 3.05902321e-7f
#define E5_4 2.06115362e-9f

typedef float v2f __attribute__((ext_vector_type(2)));

#define SINK(x) asm volatile("" :: "v"(x))

__device__ __forceinline__ float fast_exp2(float x) {
#if __has_builtin(__builtin_amdgcn_exp2f)
    return __builtin_amdgcn_exp2f(x);
#else
    float r;
    asm("v_exp_f32 %0, %1" : "=v"(r) : "v"(x));
    return r;
#endif
}
__device__ __forceinline__ float fast_sqrt(float x) {
#if __has_builtin(__builtin_amdgcn_sqrtf)
    return __builtin_amdgcn_sqrtf(x);
#else
    return sqrtf(x);
#endif
}

// Phase-resolved probe. Output is EXACT (same math as R2/R8) for any
// amplifier settings:
//  - prolog_reps: reloads the 24 neighbor-position regs (opaque zero offset)
//  - core_reps:   reruns the chain core, acc scaled by `scale` = 1/(512*core_reps)
//  - tail_reps:   reruns {QP-scale -> shfl -> LDS write -> barrier -> colsum}
//                 into temps (acc preserved), idempotent LDS writes
// Dispatch order in kernel_launch: (8,1,1) (8,9,1) (8,1,9) (8,9,9).
__global__ __launch_bounds__(256)
void rbf_probe(const float* __restrict__ pos,
               float* __restrict__ meanout,
               int core_reps, int tail_reps, int prolog_reps, float scale)
{
    __shared__ v2f red2[4][32 * 25];

    const int w    = threadIdx.x >> 6;
    const int lane = threadIdx.x & 63;
    const int row  = blockIdx.x * 4 + w;
    const int b    = row >> 9;
    const int i    = row & 511;

    const float* posb = pos + (size_t)b * 1536;

    const float pix = posb[i * 3 + 0];
    const float piy = posb[i * 3 + 1];
    const float piz = posb[i * 3 + 2];

    // ---- PROLOG phase (amplified): 24 strided global loads ----
    float jx[8], jy[8], jz[8];
#pragma unroll 1
    for (int pr = 0; pr < prolog_reps; ++pr) {
        const float* posr = posb + (pr >> 8) * 96;   // opaque 0
#pragma unroll
        for (int jj = 0; jj < 8; ++jj) {
            const int j = jj * 64 + lane;
            jx[jj] = posr[j * 3 + 0];
            jy[jj] = posr[j * 3 + 1];
            jz[jj] = posr[j * 3 + 2];
            SINK(jx[jj]); SINK(jy[jj]); SINK(jz[jj]);
        }
    }

    // ---- CORE phase (amplified): chain arithmetic only (regs in, regs out) ----
    v2f acc[25];
#pragma unroll
    for (int m = 0; m < 25; ++m) acc[m] = (v2f){0.0f, 0.0f};

#pragma unroll 1
    for (int cr = 0; cr < core_reps; ++cr) {
        const float pert = (float)(cr >> 8);          // opaque 0
#pragma unroll
        for (int jj = 0; jj < 8; ++jj) {
            const float dx = pix - jx[jj];
            const float dy = piy - jy[jj];
            const float dz = piz - jz[jj];
            const float d2 = fmaf(dx, dx, fmaf(dy, dy, fmaf(dz, dz, 1e-8f)));
            float dS = fast_sqrt(d2) * S_C + pert;
            dS = fminf(dS, 42.0f);
            const float Ap = fast_exp2(dS * TWO_DS);
#pragma unroll
            for (int c = 0; c < 5; ++c) {
                const float u  = dS - (float)c * TEN_D;
                const float t0 = fast_exp2(-(u * u));
                const float Ac  = (c == 0) ? Ap :
                                  (c == 1) ? Ap * E5_1 :
                                  (c == 2) ? Ap * E5_2 :
                                  (c == 3) ? Ap * E5_3 : Ap * E5_4;
                const float Ac2 = Ac * Ac;
                v2f g = {t0, t0 * Ac};
                acc[5 * c + 0] += g;
                const v2f M = {Ac2, Ac2};
#pragma unroll
                for (int t = 1; t < 5; ++t) {
                    g = g * M;
                    acc[5 * c + t] += g;
                }
            }
        }
    }

    // ---- TAIL phase (amplified): QP scale -> shfl -> LDS -> barrier -> colsum ----
    float meanv = 0.0f;
#pragma unroll 1
    for (int tr = 0; tr < tail_reps; ++tr) {
        const float qpert = 1.0f + (float)(tr >> 8);  // opaque 1.0
        const v2f QP[5] = {{1.0f,            0.778800783f},
                           {0.367879441f,    0.105399225f},
                           {1.83156389e-2f,  1.93045414e-3f},
                           {1.23409804e-4f,  4.78511739e-6f},
                           {1.12535175e-7f,  1.60522806e-9f}};
        v2f tacc[25];
#pragma unroll
        for (int m = 0; m < 25; ++m) {
            tacc[m] = acc[m] * (QP[m % 5] * (v2f){qpert, qpert});
            const float lx = __shfl_xor(tacc[m].x, 1);
            const float ly = __shfl_xor(tacc[m].y, 1);
            tacc[m] += (v2f){lx, ly};
        }
        if ((lane & 1) == 0) {
            v2f* myrow = &red2[w][(lane >> 1) * 25];
#pragma unroll
            for (int m = 0; m < 25; ++m) myrow[m] = tacc[m];
        }
        __syncthreads();
        meanv = 0.0f;
        if (lane < 50) {
            const float* col = (const float*)&red2[w][0] + lane;
            float s0 = 0.f, s1 = 0.f, s2 = 0.f, s3 = 0.f;
#pragma unroll
            for (int r = 0; r < 32; r += 4) {
                s0 += col[(r + 0) * 50];
                s1 += col[(r + 1) * 50];
                s2 += col[(r + 2) * 50];
                s3 += col[(r + 3) * 50];
            }
            meanv = ((s0 + s1) + (s2 + s3)) * scale;
        }
        SINK(meanv);
        __syncthreads();   // keep LDS reuse race-free across tail reps
    }

    if (lane < 50) meanout[(size_t)row * 50 + lane] = meanv;
}

// proj probe: k-loop run kreps times with mk pre-scaled by 1/kreps -> exact
// same sum (fp-rounding-level difference only). kreps=64 raises dur into the
// rocprof top-5 so proj gets its own measured row.
__global__ __launch_bounds__(256)
void proj_probe(const float* __restrict__ mean,
                const int* __restrict__ an,
                const float* __restrict__ te,
                const float* __restrict__ pw,
                const float* __restrict__ pb,
                float* __restrict__ out,
                int kreps, float kscale)
{
    const int w    = threadIdx.x >> 6;
    const int lane = threadIdx.x & 63;
    int wid = blockIdx.x * 4 + w;
    wid = __builtin_amdgcn_readfirstlane(wid);
    const int row0 = wid * 4;

    const float4 bias = reinterpret_cast<const float4*>(pb)[lane];
    float4 o[4];
#pragma unroll
    for (int r = 0; r < 4; ++r) {
        const int tok = an[row0 + r];
        const float4 t = reinterpret_cast<const float4*>(te + (size_t)tok * 256)[lane];
        o[r].x = bias.x + t.x; o[r].y = bias.y + t.y;
        o[r].z = bias.z + t.z; o[r].w = bias.w + t.w;
    }
#pragma unroll 1
    for (int kr = 0; kr < kreps; ++kr) {
        const float* pwr   = pw   + (size_t)(kr >> 8) * 256;  // opaque 0
        const float* meanr = mean + (kr >> 8);                // opaque 0
#pragma unroll
        for (int k = 0; k < 50; ++k) {
            const float4 w4 = reinterpret_cast<const float4*>(pwr + (size_t)k * 256)[lane];
#pragma unroll
            for (int r = 0; r < 4; ++r) {
                const float mk = meanr[(size_t)(row0 + r) * 50 + k] * kscale;
                o[r].x = fmaf(mk, w4.x, o[r].x);
                o[r].y = fmaf(mk, w4.y, o[r].y);
                o[r].z = fmaf(mk, w4.z, o[r].z);
                o[r].w = fmaf(mk, w4.w, o[r].w);
            }
        }
    }
#pragma unroll
    for (int r = 0; r < 4; ++r)
        reinterpret_cast<float4*>(out)[(size_t)(row0 + r) * 64 + lane] = o[r];
}

// compact fused fallback (R5-proven) in case d_ws is ever too small
__global__ __launch_bounds__(256)
void rbf_fused_fallback(const float* __restrict__ pos,
                        const int* __restrict__ an,
                        const float* __restrict__ te,
                        const float* __restrict__ pw,
                        const float* __restrict__ pb,
                        float* __restrict__ out)
{
    __shared__ v2f red2[4][32 * 25];
    __shared__ float ms[4][52];
    const int w = threadIdx.x >> 6, lane = threadIdx.x & 63;
    const int row = blockIdx.x * 4 + w, b = row >> 9, i = row & 511;
    const float* posb = pos + (size_t)b * 1536;
    const float pix = posb[i*3], piy = posb[i*3+1], piz = posb[i*3+2];
    v2f acc[25];
#pragma unroll
    for (int m = 0; m < 25; ++m) acc[m] = (v2f){0.f, 0.f};
#pragma unroll
    for (int jj = 0; jj < 8; ++jj) {
        const float* pj = posb + jj*192 + lane*3;
        const float dx = pix-pj[0], dy = piy-pj[1], dz = piz-pj[2];
        float dS = fminf(fast_sqrt(fmaf(dx,dx,fmaf(dy,dy,fmaf(dz,dz,1e-8f))))*S_C, 42.0f);
        const float Ap = fast_exp2(dS*TWO_DS);
#pragma unroll
        for (int c = 0; c < 5; ++c) {
            const float u = dS - (float)c*TEN_D;
            const float t0 = fast_exp2(-(u*u));
            const float Ac = (c==0)?Ap:(c==1)?Ap*E5_1:(c==2)?Ap*E5_2:(c==3)?Ap*E5_3:Ap*E5_4;
            const float Ac2 = Ac*Ac;
            v2f g = {t0, t0*Ac};
            acc[5*c] += g;
            const v2f M = {Ac2, Ac2};
#pragma unroll
            for (int t = 1; t < 5; ++t) { g = g*M; acc[5*c+t] += g; }
        }
    }
    const v2f QP[5] = {{1.0f,0.778800783f},{0.367879441f,0.105399225f},
                       {1.83156389e-2f,1.93045414e-3f},{1.23409804e-4f,4.78511739e-6f},
                       {1.12535175e-7f,1.60522806e-9f}};
#pragma unroll
    for (int m = 0; m < 25; ++m) {
        acc[m] = acc[m]*QP[m%5];
        const float lx = __shfl_xor(acc[m].x,1), ly = __shfl_xor(acc[m].y,1);
        acc[m] += (v2f){lx,ly};
    }
    if ((lane&1)==0) {
        v2f* myrow = &red2[w][(lane>>1)*25];
#pragma unroll
        for (int m = 0; m < 25; ++m) myrow[m] = acc[m];
    }
    __syncthreads();
    if (lane < 50) {
        const float* col = (const float*)&red2[w][0] + lane;
        float s = 0.f;
#pragma unroll
        for (int r = 0; r < 32; ++r) s += col[r*50];
        ms[w][lane] = s * (1.0f/512.0f);
    }
    __syncthreads();
    const int tok = an[row];
    float4 o = reinterpret_cast<const float4*>(pb)[lane];
    const float4 t = reinterpret_cast<const float4*>(te + (size_t)tok*256)[lane];
    o.x += t.x; o.y += t.y; o.z += t.z; o.w += t.w;
#pragma unroll
    for (int k = 0; k < 50; ++k) {
        const float mk = ms[w][k];
        const float4 w4 = reinterpret_cast<const float4*>(pw + k*256)[lane];
        o.x = fmaf(mk,w4.x,o.x); o.y = fmaf(mk,w4.y,o.y);
        o.z = fmaf(mk,w4.z,o.z); o.w = fmaf(mk,w4.w,o.w);
    }
    reinterpret_cast<float4*>(out)[(size_t)row*64 + lane] = o;
}

extern "C" void kernel_launch(void* const* d_in, const int* in_sizes, int n_in,
                              void* d_out, int out_size, void* d_ws, size_t ws_size,
                              hipStream_t stream)
{
    const int*   an  = (const int*)  d_in[0];
    const float* pos = (const float*)d_in[1];
    const float* te  = (const float*)d_in[2];
    const float* pw  = (const float*)d_in[3];
    const float* pb  = (const float*)d_in[4];
    float* out = (float*)d_out;

    const size_t mean_bytes = (size_t)8192 * 50 * sizeof(float);
    if (ws_size >= mean_bytes) {
        float* mean = (float*)d_ws;
        const float sc = 1.0f / (512.0f * 8.0f);
        // dispatch order (match to rocprof _ord):
        // Ka: core x8            -> baseline with amplified core
        // Kb: core x8, tail x9   -> Kb-Ka = 8*T
        // Kc: core x8, prolog x9 -> Kc-Ka = 8*P
        // Kd: both x9            -> linearity check
        rbf_probe<<<2048, 256, 0, stream>>>(pos, mean, 8, 1, 1, sc);
        rbf_probe<<<2048, 256, 0, stream>>>(pos, mean, 8, 9, 1, sc);
        rbf_probe<<<2048, 256, 0, stream>>>(pos, mean, 8, 1, 9, sc);
        rbf_probe<<<2048, 256, 0, stream>>>(pos, mean, 8, 9, 9, sc);
        // proj with k-loop x64 (exact output, measured row in top-5)
        proj_probe<<<512, 256, 0, stream>>>(mean, an, te, pw, pb, out, 64, 1.0f/64.0f);
    } else {
        rbf_fused_fallback<<<2048, 256, 0, stream>>>(pos, an, te, pw, pb, out);
    }
}